// Round 4
// baseline (418.172 us; speedup 1.0000x reference)
//
#include <hip/hip_runtime.h>

// Problem: x (512,3,224,224) f32; W (1,768) f32; b (1,) f32; P=16.
// out[b*196 + o/768] = bias + sum_k W[o%768]*A'[o]; within a (b,p1) slab of
// 9408 elems: u = p2*588 + c*196 + h*14 + w; x col = 16w+p2, row = 16h+p1.
constexpr int CHW     = 150528;   // 3*224*224
constexpr int CPLANE  = 50176;    // 224*224
constexpr int OUT_PB  = 196;
constexpr int BLOCK_O = 9408;     // 16*588
constexpr int NSLAB   = 4;        // slabs per persistent block (pipeline depth)

__global__ __launch_bounds__(512)
void patch_score_kernel(const float* __restrict__ x,
                        const float* __restrict__ W,
                        const float* __restrict__ bias,
                        float* __restrict__ out) {
    __shared__ float lds[BLOCK_O];   // 37,632 B; regs are the 2nd pipeline buffer

    const int tid = threadIdx.x;
    const int g0  = blockIdx.x * NSLAB;      // first slab id; slab g -> b=g>>4, p1=g&15

    // ---- Slab-invariant per-thread addressing (f = tid + i*512):
    // seg = c*14+h (56 float4 per 224-float row), off in row; LDS scatter
    // base = (off&3)*4*588 + c*196 + h*14 + (off>>2); elems e at base+588e.
    int goff[5], lbase[5];
#pragma unroll
    for (int i = 0; i < 5; ++i) {
        const int f   = tid + i * 512;
        const int seg = f / 56;
        const int off = f - seg * 56;
        const int c   = seg / 14;
        const int h   = seg - c * 14;
        goff[i]  = c * CPLANE + h * 3584 + 4 * off;
        lbase[i] = (off & 3) * 2352 + c * 196 + h * 14 + (off >> 2);
    }
    const bool tail = (tid < 304);           // 2352 = 4*512 + 304

    const int lane = tid & 63;
    const int wv   = tid >> 6;               // 0..7
    float wreg[12];
#pragma unroll
    for (int i = 0; i < 12; ++i) wreg[i] = W[i * 64 + lane];
    const float bv = bias[0];

    // ---- prologue: load + stage slab 0
    float4 r[5];
    {
        const int g = g0;
        const float* xb = x + (size_t)(g >> 4) * CHW + (g & 15) * 224;
#pragma unroll
        for (int i = 0; i < 4; ++i) r[i] = *(const float4*)(xb + goff[i]);
        if (tail) r[4] = *(const float4*)(xb + goff[4]);
#pragma unroll
        for (int i = 0; i < 4; ++i) {
            float* d = &lds[lbase[i]];
            d[0] = r[i].x; d[588] = r[i].y; d[1176] = r[i].z; d[1764] = r[i].w;
        }
        if (tail) {
            float* d = &lds[lbase[4]];
            d[0] = r[4].x; d[588] = r[4].y; d[1176] = r[4].z; d[1764] = r[4].w;
        }
    }

#pragma unroll
    for (int s = 0; s < NSLAB; ++s) {
        __syncthreads();                     // lds now holds slab s

        // Fire next slab's loads NOW -> HBM transfers overlap the compute below.
        if (s + 1 < NSLAB) {
            const int g = g0 + s + 1;
            const float* xb = x + (size_t)(g >> 4) * CHW + (g & 15) * 224;
#pragma unroll
            for (int i = 0; i < 4; ++i) r[i] = *(const float4*)(xb + goff[i]);
            if (tail) r[4] = *(const float4*)(xb + goff[4]);
        }

        // ---- compute on slab s: rows j overlapping [o_base, o_base+9408)
        {
            const int g  = g0 + s;
            const int b  = g >> 4;
            const int p1 = g & 15;
            const int o_base  = p1 * BLOCK_O;
            const int j_start = o_base / 768;
            const int j_end   = (o_base + BLOCK_O - 1) / 768;

            for (int j = j_start + wv; j <= j_end; j += 8) {
                const int kb = j * 768 - o_base;
                float acc = 0.0f;
                const bool interior = (kb >= 0) && (kb <= BLOCK_O - 768);
                if (interior) {
                    const float* p = &lds[kb + lane];
#pragma unroll
                    for (int i = 0; i < 12; ++i) acc += p[i * 64] * wreg[i];
                } else {
#pragma unroll
                    for (int i = 0; i < 12; ++i) {
                        const int u = kb + i * 64 + lane;
                        if (u >= 0 && u < BLOCK_O) acc += lds[u] * wreg[i];
                    }
                }
#pragma unroll
                for (int off = 32; off > 0; off >>= 1)
                    acc += __shfl_down(acc, off, 64);
                if (lane == 0) {
                    float* dst = &out[b * OUT_PB + j];
                    if (interior)    *dst = acc + bv;          // row fully ours
                    else if (kb > 0) atomicAdd(dst, acc + bv); // start-owner adds bias
                    else             atomicAdd(dst, acc);      // end-owner
                }
            }
        }

        __syncthreads();                     // all waves done reading slab s

        // Scatter the (now landed) next slab into LDS.
        if (s + 1 < NSLAB) {
#pragma unroll
            for (int i = 0; i < 4; ++i) {
                float* d = &lds[lbase[i]];
                d[0] = r[i].x; d[588] = r[i].y; d[1176] = r[i].z; d[1764] = r[i].w;
            }
            if (tail) {
                float* d = &lds[lbase[4]];
                d[0] = r[4].x; d[588] = r[4].y; d[1176] = r[4].z; d[1764] = r[4].w;
            }
        }
    }
}

extern "C" void kernel_launch(void* const* d_in, const int* in_sizes, int n_in,
                              void* d_out, int out_size, void* d_ws, size_t ws_size,
                              hipStream_t stream) {
    const float* x    = (const float*)d_in[0];
    const float* W    = (const float*)d_in[1];
    const float* bias = (const float*)d_in[2];
    float* out = (float*)d_out;

    // Block-boundary rows accumulate via atomicAdd -> zero-init output.
    hipMemsetAsync(out, 0, (size_t)out_size * sizeof(float), stream);

    // 8192 slabs / NSLAB per block = 2048 persistent blocks of 512 threads.
    patch_score_kernel<<<8192 / NSLAB, 512, 0, stream>>>(x, W, bias, out);
}

// Round 5
// 407.691 us; speedup vs baseline: 1.0257x; 1.0257x over previous
//
#include <hip/hip_runtime.h>

// Problem: x (512,3,224,224) f32; W (1,768) f32; b (1,) f32; P=16.
// out[b*196 + o/768] = bias + sum_k W[o%768]*A'[o]; within a (b,p1) slab of
// 9408 elems: u = p2*588 + c*196 + h*14 + w; x col = 16w+p2, row = 16h+p1.
//
// Exact partition: 49*768 == 4*9408, so slabs p1 in [4q,4q+4) of one batch
// produce exactly output rows [49q, 49q+49) -> one block = (b,q), no row
// crosses a block boundary => no atomics, no output memset. Rows crossing an
// internal slab boundary (rel rows 12/24/36) are carried in registers.
constexpr int CHW     = 150528;   // 3*224*224
constexpr int CPLANE  = 50176;    // 224*224
constexpr int OUT_PB  = 196;
constexpr int BLOCK_O = 9408;     // 16*588

__global__ __launch_bounds__(512)
void patch_score_kernel(const float* __restrict__ x,
                        const float* __restrict__ W,
                        const float* __restrict__ bias,
                        float* __restrict__ out) {
    __shared__ float lds[BLOCK_O];   // 37,632 B; regs are the 2nd pipeline buffer

    const int tid = threadIdx.x;
    const int b   = blockIdx.x >> 2;
    const int q   = blockIdx.x & 3;          // slabs p1 = 4q+s, s=0..3

    // Slab-invariant per-thread addressing (f = tid + i*512, f < 2352):
    // seg = c*14+h (56 float4 per 224-float row), off in row.
    // LDS scatter base = (4off&15)*588 + c*196 + h*14 + (off>>2); elems at +588e.
    int goff[5], lbase[5];
#pragma unroll
    for (int i = 0; i < 5; ++i) {
        const int f   = tid + i * 512;
        const int seg = f / 56;
        const int off = f - seg * 56;
        const int c   = seg / 14;
        const int h   = seg - c * 14;
        goff[i]  = c * CPLANE + h * 3584 + 4 * off;
        lbase[i] = (off & 3) * 2352 + c * 196 + h * 14 + (off >> 2);
    }
    const bool tail = (tid < 304);           // 2352 = 4*512 + 304

    const int lane = tid & 63;
    const int wv   = tid >> 6;               // 0..7
    float wreg[12];
#pragma unroll
    for (int i = 0; i < 12; ++i) wreg[i] = W[i * 64 + lane];
    const float bv = bias[0];

    const float* xrow = x + (size_t)b * CHW + (size_t)(4 * q) * 224;
    float* outg = out + b * OUT_PB + 49 * q;

    // ---- prologue: load + stage slab s=0
    float4 r[5];
#pragma unroll
    for (int i = 0; i < 4; ++i) r[i] = *(const float4*)(xrow + goff[i]);
    if (tail) r[4] = *(const float4*)(xrow + goff[4]);
#pragma unroll
    for (int i = 0; i < 4; ++i) {
        float* d = &lds[lbase[i]];
        d[0] = r[i].x; d[588] = r[i].y; d[1176] = r[i].z; d[1764] = r[i].w;
    }
    if (tail) {
        float* d = &lds[lbase[4]];
        d[0] = r[4].x; d[588] = r[4].y; d[1176] = r[4].z; d[1764] = r[4].w;
    }

    float carry = 0.0f;                      // per-lane partial of the crossing row

#pragma unroll
    for (int s = 0; s < 4; ++s) {
        __syncthreads();                     // lds now holds slab s

        // Fire next slab's loads NOW -> HBM transfer overlaps compute below.
        if (s < 3) {
            const float* xb = xrow + (s + 1) * 224;
#pragma unroll
            for (int i = 0; i < 4; ++i) r[i] = *(const float4*)(xb + goff[i]);
            if (tail) r[4] = *(const float4*)(xb + goff[4]);
        }

        // ---- compute: rel rows j in [j_lo, j_hi], kb = 768j - 9408s.
        const int j_lo = (49 * s) >> 2;          // 0,12,24,36
        const int j_hi = (49 * (s + 1) - 1) >> 2; // 12,24,36,48
        for (int j = j_lo + ((wv - j_lo) & 7); j <= j_hi; j += 8) {
            const int kb = 768 * j - 9408 * s;
            if (kb >= 0 && kb <= BLOCK_O - 768) {         // interior row
                const float* p = &lds[kb + lane];
                float acc = 0.0f;
#pragma unroll
                for (int i = 0; i < 12; ++i) acc += p[i * 64] * wreg[i];
#pragma unroll
                for (int off = 32; off > 0; off >>= 1)
                    acc += __shfl_down(acc, off, 64);
                if (lane == 0) outg[j] = acc + bv;
            } else if (kb > BLOCK_O - 768) {              // tail -> carry (j_hi, s<3)
                float acc = 0.0f;
#pragma unroll
                for (int i = 0; i < 12; ++i) {
                    const int u = kb + i * 64 + lane;
                    if (u < BLOCK_O) acc += lds[u] * wreg[i];
                }
                carry = acc;
            } else {                                      // head: finish carried row
                float acc = carry;
#pragma unroll
                for (int i = 0; i < 12; ++i) {
                    const int u = kb + i * 64 + lane;
                    if (u >= 0) acc += lds[u] * wreg[i];
                }
#pragma unroll
                for (int off = 32; off > 0; off >>= 1)
                    acc += __shfl_down(acc, off, 64);
                if (lane == 0) outg[j] = acc + bv;
                carry = 0.0f;
            }
        }

        __syncthreads();                     // all waves done reading slab s

        // Scatter the (landed) next slab into LDS.
        if (s < 3) {
#pragma unroll
            for (int i = 0; i < 4; ++i) {
                float* d = &lds[lbase[i]];
                d[0] = r[i].x; d[588] = r[i].y; d[1176] = r[i].z; d[1764] = r[i].w;
            }
            if (tail) {
                float* d = &lds[lbase[4]];
                d[0] = r[4].x; d[588] = r[4].y; d[1176] = r[4].z; d[1764] = r[4].w;
            }
        }
    }
}

extern "C" void kernel_launch(void* const* d_in, const int* in_sizes, int n_in,
                              void* d_out, int out_size, void* d_ws, size_t ws_size,
                              hipStream_t stream) {
    const float* x    = (const float*)d_in[0];
    const float* W    = (const float*)d_in[1];
    const float* bias = (const float*)d_in[2];
    float* out = (float*)d_out;

    // One block per (batch, q): 512*4 = 2048 blocks. Every output row is
    // written exactly once by a plain store -> no memset, no atomics.
    patch_score_kernel<<<512 * 4, 512, 0, stream>>>(x, W, bias, out);
}